// Round 12
// baseline (83.526 us; speedup 1.0000x reference)
//
#include <hip/hip_runtime.h>
#include <hip/hip_bf16.h>
#include <cstdint>
#include <cstddef>

#define NSPIN 2
#define NPART 16
#define DDIM  512
#define NION  8

// Per-wave private LDS slice (floats): LINP[16]x20, LINJ[16]x20, ENV[16]x20, DETS 16
#define WSLICE     976
#define LDS_FLOATS (4 * WSLICE)
#define LDS_BYTES  (LDS_FLOATS * 4)      // 15616 B

// ws float layout: [0,16384) = W bf16 fragments (4096 uint4); [16384,18432) = gram
#define WS_GRAM_F  16384

typedef short bf16x8 __attribute__((ext_vector_type(8)));
typedef float f32x4  __attribute__((ext_vector_type(4)));

__device__ __forceinline__ short bfc(float x) {  // f32 -> bf16 (RNE) [prep only]
    unsigned u = __float_as_uint(x);
    u += 0x7FFFu + ((u >> 16) & 1u);
    return (short)(u >> 16);
}

union AFU { bf16x8 v; __hip_bfloat162 h[4]; };

__device__ __forceinline__ bf16x8 cvt8(const float4& a, const float4& b) {
    AFU u;
    u.h[0] = __float22bfloat162_rn(make_float2(a.x, a.y));
    u.h[1] = __float22bfloat162_rn(make_float2(a.z, a.w));
    u.h[2] = __float22bfloat162_rn(make_float2(b.x, b.y));
    u.h[3] = __float22bfloat162_rn(make_float2(b.z, b.w));
    return u.v;
}

// 16-lane-row rotate + unsigned max (VALU pipe)
#define DPPMAXU(k, ctrl) { unsigned o_ = (unsigned)__builtin_amdgcn_update_dpp(0, (int)(k), (ctrl), 0xF, 0xF, true); (k) = (k) > o_ ? (k) : o_; }

// ---- prep: W fragments (blocks 0..15) + gram table (block 16) ----
__global__ void __launch_bounds__(256)
prep_kernel(const float* __restrict__ WL, const float* __restrict__ AE,
            const float* __restrict__ WI, float* __restrict__ WSF)
{
    const int t = threadIdx.x;
    if (blockIdx.x < 16) {
        int slot = blockIdx.x * 256 + t;                 // 0..4095
        int spin = slot >> 11;
        int rem  = slot & 2047;
        int half = rem >> 10;
        int ks   = (rem >> 6) & 15;
        int lane = rem & 63;
        int cc2  = lane & 15, hh = lane >> 4;
        const float* src = WL + (size_t)spin * (2 * DDIM * NPART)
                         + ((size_t)(half * 512 + ks * 32 + hh * 8)) * NPART + cc2;
        ushort u[8];
        #pragma unroll
        for (int e = 0; e < 8; ++e) u[e] = (ushort)bfc(src[e * NPART]);
        uint4 pk;
        pk.x = (unsigned)u[0] | ((unsigned)u[1] << 16);
        pk.y = (unsigned)u[2] | ((unsigned)u[3] << 16);
        pk.z = (unsigned)u[4] | ((unsigned)u[5] << 16);
        pk.w = (unsigned)u[6] | ((unsigned)u[7] << 16);
        ((uint4*)WSF)[slot] = pk;
    } else {
        // gram: t = s*128 + ke*8 + i
        int s  = t >> 7;
        int ke = (t >> 3) & 15;
        int i  = t & 7;
        const float* Ag = AE + (size_t)s * (9 * NION * NPART);
        float a00 = Ag[((0 * 3 + 0) * NION + i) * NPART + ke];
        float a01 = Ag[((0 * 3 + 1) * NION + i) * NPART + ke];
        float a02 = Ag[((0 * 3 + 2) * NION + i) * NPART + ke];
        float a10 = Ag[((1 * 3 + 0) * NION + i) * NPART + ke];
        float a11 = Ag[((1 * 3 + 1) * NION + i) * NPART + ke];
        float a12 = Ag[((1 * 3 + 2) * NION + i) * NPART + ke];
        float a20 = Ag[((2 * 3 + 0) * NION + i) * NPART + ke];
        float a21 = Ag[((2 * 3 + 1) * NION + i) * NPART + ke];
        float a22 = Ag[((2 * 3 + 2) * NION + i) * NPART + ke];
        float* g = WSF + WS_GRAM_F + t * 8;
        g[0] = a00 * a00 + a01 * a01 + a02 * a02;
        g[1] = a10 * a10 + a11 * a11 + a12 * a12;
        g[2] = a20 * a20 + a21 * a21 + a22 * a22;
        g[3] = a00 * a10 + a01 * a11 + a02 * a12;
        g[4] = a00 * a20 + a01 * a21 + a02 * a22;
        g[5] = a10 * a20 + a11 * a21 + a12 * a22;
        g[6] = WI[(size_t)s * (NION * NPART) + i * NPART + ke];
        g[7] = 0.f;
    }
}

// Zero-barrier kernel: each wave owns one b end-to-end; waves drift out of
// phase so det's DS-pipe time hides under other waves' HBM traffic.
__global__ void __launch_bounds__(256, 4)
ppdet_kernel(const float* __restrict__ EQ, const float* __restrict__ RE,
             const float* __restrict__ WSF, const float* __restrict__ BL,
             float* __restrict__ OUT)
{
    extern __shared__ float ls[];
    const int t  = threadIdx.x;
    const int s  = blockIdx.x >> 9;           // spin
    const int b0 = (blockIdx.x & 511) * 4;    // 4 b's per block (one per wave)

    const int l  = t & 63;                    // lane in wave
    const int w  = t >> 6;                    // wave id: owns b = b0+w
    const int b  = b0 + w;
    const int c  = l & 15;                    // MFMA col lane / k index
    const int h4 = l >> 4;                    // MFMA k-group / group id
    const int jr = l & 15;                    // row j (env/det)
    const int g  = l >> 4;                    // 16-lane group in wave

    float* wls = ls + w * WSLICE;             // private slice, no barriers needed
    // layout: [0,320) LINP (stride 20), [320,640) LINJ, [640,960) ENV, [960,976) DETS

    // ---- GEMM via MFMA: x + W-frags straight from global (R6-proven path) ----
    {
        const float* xg  = EQ + ((size_t)(b * 32 + s * 16 + c)) * DDIM + h4 * 8;
        const uint4* wb1 = (const uint4*)WSF + (size_t)s * 2048;
        const uint4* wb2 = wb1 + 1024;
        f32x4 accp = {0.f, 0.f, 0.f, 0.f}, accj = {0.f, 0.f, 0.f, 0.f};
        #pragma unroll
        for (int kb = 0; kb < 4; ++kb) {
            float4 xa[8];
            uint4 w1v[4], w2v[4];
            #pragma unroll
            for (int u = 0; u < 4; ++u) {
                xa[2 * u]     = *(const float4*)(xg + (kb * 4 + u) * 32);
                xa[2 * u + 1] = *(const float4*)(xg + (kb * 4 + u) * 32 + 4);
                w1v[u] = wb1[(kb * 4 + u) * 64 + l];
                w2v[u] = wb2[(kb * 4 + u) * 64 + l];
            }
            #pragma unroll
            for (int u = 0; u < 4; ++u) {
                bf16x8 af = cvt8(xa[2 * u], xa[2 * u + 1]);
                accp = __builtin_amdgcn_mfma_f32_16x16x32_bf16(af, *(bf16x8*)&w1v[u], accp, 0, 0, 0);
                accj = __builtin_amdgcn_mfma_f32_16x16x32_bf16(af, *(bf16x8*)&w2v[u], accj, 0, 0, 0);
            }
        }
        const float blv = BL[s * NPART + c];
        #pragma unroll
        for (int q = 0; q < 4; ++q) {     // C: row(particle/j) = h4*4+q, col(k) = c
            wls[(h4 * 4 + q) * 20 + c]        = accp[q];
            wls[320 + (h4 * 4 + q) * 20 + c]  = accj[q] + blv;
        }
    }

    // ---- env: lane (jr, g); r-row loaded once, gram broadcast from global ----
    {
        float rr[24];
        const float* rrow = RE + ((size_t)(b * 32 + s * 16 + jr)) * 24;
        #pragma unroll
        for (int m = 0; m < 6; ++m) {
            float4 v = ((const float4*)rrow)[m];
            rr[m * 4 + 0] = v.x; rr[m * 4 + 1] = v.y;
            rr[m * 4 + 2] = v.z; rr[m * 4 + 3] = v.w;
        }
        #pragma unroll
        for (int kx = 0; kx < 4; ++kx) {
            const int ke2 = g + kx * 4;
            const float4* gp = (const float4*)(WSF + WS_GRAM_F + s * 1024 + ke2 * 64);
            float ev = 0.f;
            #pragma unroll
            for (int i = 0; i < 8; ++i) {
                float4 gA = gp[2 * i];           // G0,G1,G2,G3
                float4 gB = gp[2 * i + 1];       // G4,G5,wir,0
                float r0 = rr[i * 3 + 0], r1 = rr[i * 3 + 1], r2 = rr[i * 3 + 2];
                float ss = r0 * r0 * gA.x;
                ss = fmaf(r1 * r1, gA.y, ss);
                ss = fmaf(r2 * r2, gA.z, ss);
                float tcr = r0 * r1 * gA.w;
                tcr = fmaf(r0 * r2, gB.x, tcr);
                tcr = fmaf(r1 * r2, gB.y, tcr);
                ss = fmaf(2.f, tcr, ss);
                ss = fmaxf(ss, 0.f);
                ev = fmaf(gB.z, __expf(-__builtin_amdgcn_sqrtf(ss)), ev);
            }
            wls[640 + jr * 20 + ke2] = ev;
        }
    }

    // wave-internal ordering of LDS writes (LIN/ENV) before det reads — no barrier
    asm volatile("s_waitcnt lgkmcnt(0)" ::: "memory");

    // ---- det: 4 passes x 4 matrices (p = pp*4+g); DPP argmax + bpermute bcast ----
    const int lanebase4 = (l & 48) << 2;     // byte addr of in-wave group base
    #pragma unroll 1
    for (int pp = 0; pp < 4; ++pp) {
        const int p = pp * 4 + g;
        float Mr[16];
        const float* lp = wls + p * 20;          // broadcast within group
        const float* lj = wls + 320 + jr * 20;
        const float* ev = wls + 640 + jr * 20;
        #pragma unroll
        for (int cq = 0; cq < 4; ++cq) {
            float4 a  = *(const float4*)(lp + cq * 4);
            float4 bb = *(const float4*)(lj + cq * 4);
            float4 e  = *(const float4*)(ev + cq * 4);
            Mr[cq * 4 + 0] = (a.x + bb.x) * e.x;
            Mr[cq * 4 + 1] = (a.y + bb.y) * e.y;
            Mr[cq * 4 + 2] = (a.z + bb.z) * e.z;
            Mr[cq * 4 + 3] = (a.w + bb.w) * e.w;
        }
        float detv = 1.f;
        unsigned sel = 0u;
        int inv = 0;
        bool msel = false;
        #pragma unroll
        for (int cc = 0; cc < 16; ++cc) {
            unsigned key = msel ? 0u
                : ((__float_as_uint(fabsf(Mr[cc])) & 0xFFFFFFF0u) | (unsigned)jr);
            DPPMAXU(key, 0x121); DPPMAXU(key, 0x122); DPPMAXU(key, 0x124); DPPMAXU(key, 0x128);
            const int idx = (int)(key & 15u);
            const bool ispiv = (jr == idx) && !msel;
            const int srcaddr = lanebase4 | (idx << 2);
            float Pr[16];
            #pragma unroll
            for (int k2 = cc; k2 < 16; ++k2)
                Pr[k2] = __int_as_float(__builtin_amdgcn_ds_bpermute(
                             srcaddr, __float_as_int(Mr[k2])));
            const float pv = Pr[cc];
            const float f = (msel || ispiv || pv == 0.f) ? 0.f
                          : Mr[cc] * __builtin_amdgcn_rcpf(pv);
            inv += __popc(sel >> (idx + 1));
            sel |= (1u << idx);
            msel = msel || ispiv;
            detv *= pv;
            #pragma unroll
            for (int k2 = cc + 1; k2 < 16; ++k2)
                Mr[k2] = fmaf(-f, Pr[k2], Mr[k2]);
        }
        if (inv & 1) detv = -detv;
        if (jr == 0) wls[960 + p] = detv;
    }

    // DETS writes -> epilogue reads (wave-internal)
    asm volatile("s_waitcnt lgkmcnt(0)" ::: "memory");

    // ---- epilogue: out = x * det; non-temporal stores (write-once) ----
    {
        const size_t base = ((size_t)(b * 32 + s * 16)) * DDIM;
        const f32x4* src4 = (const f32x4*)(EQ + base);
        f32x4* dst4 = (f32x4*)(OUT + base);
        #pragma unroll
        for (int i2 = 0; i2 < 32; ++i2) {
            int f4i = i2 * 64 + l;
            float dt = wls[960 + (f4i >> 7)];
            f32x4 xv = src4[f4i];
            f32x4 o = xv * dt;
            __builtin_nontemporal_store(o, dst4 + f4i);
        }
    }
}

extern "C" void kernel_launch(void* const* d_in, const int* in_sizes, int n_in,
                              void* d_out, int out_size, void* d_ws, size_t ws_size,
                              hipStream_t stream) {
    const float* EQ = (const float*)d_in[0];
    const float* RE = (const float*)d_in[1];
    const float* WL = (const float*)d_in[2];
    const float* BL = (const float*)d_in[3];
    const float* AE = (const float*)d_in[4];
    const float* WI = (const float*)d_in[5];
    float* OUT = (float*)d_out;
    float* WSF = (float*)d_ws;   // 16384 + 2048 floats = 73728 B
    (void)in_sizes; (void)n_in; (void)out_size; (void)ws_size;

    prep_kernel<<<dim3(17), dim3(256), 0, stream>>>(WL, AE, WI, WSF);
    ppdet_kernel<<<dim3(1024), dim3(256), LDS_BYTES, stream>>>(EQ, RE, WSF, BL, OUT);
}

// Round 13
// 81.949 us; speedup vs baseline: 1.0192x; 1.0192x over previous
//
#include <hip/hip_runtime.h>
#include <hip/hip_bf16.h>
#include <cstdint>
#include <cstddef>

#define NSPIN 2
#define NPART 16
#define DDIM  512
#define NION  8
#define NB    4

// LDS float offsets (total 7616 floats = 30464 B)
#define RS_OFF     0                      // [ib(4)][e(24)][j(16)] = 1536
#define GRAM_OFF   1536                   // [ke(16)] stride 72 = 1152
#define LINP_OFF   (GRAM_OFF + 1152)      // [ib(4)][p(16)] stride 20 = 1280
#define LINJ_OFF   (LINP_OFF + 1280)      // [ib(4)][j(16)] stride 20 = 1280
#define ENV_OFF    (LINJ_OFF + 1280)      // 1280
#define DETS_OFF   (ENV_OFF + 1280)       // 64
#define LDS_FLOATS (DETS_OFF + 64)
#define LDS_BYTES  (LDS_FLOATS * 4)

// ws float layout: [0,16384) = W bf16 fragments (4096 uint4); [16384,18432) = gram
#define WS_GRAM_F  16384

typedef short bf16x8 __attribute__((ext_vector_type(8)));
typedef float f32x4  __attribute__((ext_vector_type(4)));

__device__ __forceinline__ short bfc(float x) {  // f32 -> bf16 (RNE) [prep only]
    unsigned u = __float_as_uint(x);
    u += 0x7FFFu + ((u >> 16) & 1u);
    return (short)(u >> 16);
}

union AFU { bf16x8 v; __hip_bfloat162 h[4]; };

__device__ __forceinline__ bf16x8 cvt8(const float4& a, const float4& b) {
    AFU u;
    u.h[0] = __float22bfloat162_rn(make_float2(a.x, a.y));
    u.h[1] = __float22bfloat162_rn(make_float2(a.z, a.w));
    u.h[2] = __float22bfloat162_rn(make_float2(b.x, b.y));
    u.h[3] = __float22bfloat162_rn(make_float2(b.z, b.w));
    return u.v;
}

// 16-lane-row rotate + unsigned max (VALU pipe)
#define DPPMAXU(k, ctrl) { unsigned o_ = (unsigned)__builtin_amdgcn_update_dpp(0, (int)(k), (ctrl), 0xF, 0xF, true); (k) = (k) > o_ ? (k) : o_; }

// Named straight-line load/compute batches (no arrays -> compiler keeps issue order)
#define XLD(p, kb) \
    float4 p##0 = *(const float4*)(xg + (kb) * 128 +   0); \
    float4 p##1 = *(const float4*)(xg + (kb) * 128 +   4); \
    float4 p##2 = *(const float4*)(xg + (kb) * 128 +  32); \
    float4 p##3 = *(const float4*)(xg + (kb) * 128 +  36); \
    float4 p##4 = *(const float4*)(xg + (kb) * 128 +  64); \
    float4 p##5 = *(const float4*)(xg + (kb) * 128 +  68); \
    float4 p##6 = *(const float4*)(xg + (kb) * 128 +  96); \
    float4 p##7 = *(const float4*)(xg + (kb) * 128 + 100);

#define WLD(p, kb) \
    uint4 p##a0 = wb1[((kb) * 4 + 0) * 64 + l]; \
    uint4 p##a1 = wb1[((kb) * 4 + 1) * 64 + l]; \
    uint4 p##a2 = wb1[((kb) * 4 + 2) * 64 + l]; \
    uint4 p##a3 = wb1[((kb) * 4 + 3) * 64 + l]; \
    uint4 p##b0 = wb2[((kb) * 4 + 0) * 64 + l]; \
    uint4 p##b1 = wb2[((kb) * 4 + 1) * 64 + l]; \
    uint4 p##b2 = wb2[((kb) * 4 + 2) * 64 + l]; \
    uint4 p##b3 = wb2[((kb) * 4 + 3) * 64 + l];

#define MF(af, wv, acc) acc = __builtin_amdgcn_mfma_f32_16x16x32_bf16((af), *(const bf16x8*)&(wv), (acc), 0, 0, 0)

#define COMP(x, p) { \
    bf16x8 af0 = cvt8(x##0, x##1); MF(af0, p##a0, accp); MF(af0, p##b0, accj); \
    bf16x8 af1 = cvt8(x##2, x##3); MF(af1, p##a1, accp); MF(af1, p##b1, accj); \
    bf16x8 af2 = cvt8(x##4, x##5); MF(af2, p##a2, accp); MF(af2, p##b2, accj); \
    bf16x8 af3 = cvt8(x##6, x##7); MF(af3, p##a3, accp); MF(af3, p##b3, accj); }

// ---- prep: W fragments (blocks 0..15) + gram table (block 16) ----
__global__ void __launch_bounds__(256)
prep_kernel(const float* __restrict__ WL, const float* __restrict__ AE,
            const float* __restrict__ WI, float* __restrict__ WSF)
{
    const int t = threadIdx.x;
    if (blockIdx.x < 16) {
        int slot = blockIdx.x * 256 + t;                 // 0..4095
        int spin = slot >> 11;
        int rem  = slot & 2047;
        int half = rem >> 10;
        int ks   = (rem >> 6) & 15;
        int lane = rem & 63;
        int cc2  = lane & 15, hh = lane >> 4;
        const float* src = WL + (size_t)spin * (2 * DDIM * NPART)
                         + ((size_t)(half * 512 + ks * 32 + hh * 8)) * NPART + cc2;
        ushort u[8];
        #pragma unroll
        for (int e = 0; e < 8; ++e) u[e] = (ushort)bfc(src[e * NPART]);
        uint4 pk;
        pk.x = (unsigned)u[0] | ((unsigned)u[1] << 16);
        pk.y = (unsigned)u[2] | ((unsigned)u[3] << 16);
        pk.z = (unsigned)u[4] | ((unsigned)u[5] << 16);
        pk.w = (unsigned)u[6] | ((unsigned)u[7] << 16);
        ((uint4*)WSF)[slot] = pk;
    } else {
        // gram: t = s*128 + ke*8 + i
        int s  = t >> 7;
        int ke = (t >> 3) & 15;
        int i  = t & 7;
        const float* Ag = AE + (size_t)s * (9 * NION * NPART);
        float a00 = Ag[((0 * 3 + 0) * NION + i) * NPART + ke];
        float a01 = Ag[((0 * 3 + 1) * NION + i) * NPART + ke];
        float a02 = Ag[((0 * 3 + 2) * NION + i) * NPART + ke];
        float a10 = Ag[((1 * 3 + 0) * NION + i) * NPART + ke];
        float a11 = Ag[((1 * 3 + 1) * NION + i) * NPART + ke];
        float a12 = Ag[((1 * 3 + 2) * NION + i) * NPART + ke];
        float a20 = Ag[((2 * 3 + 0) * NION + i) * NPART + ke];
        float a21 = Ag[((2 * 3 + 1) * NION + i) * NPART + ke];
        float a22 = Ag[((2 * 3 + 2) * NION + i) * NPART + ke];
        float* g = WSF + WS_GRAM_F + t * 8;
        g[0] = a00 * a00 + a01 * a01 + a02 * a02;
        g[1] = a10 * a10 + a11 * a11 + a12 * a12;
        g[2] = a20 * a20 + a21 * a21 + a22 * a22;
        g[3] = a00 * a10 + a01 * a11 + a02 * a12;
        g[4] = a00 * a20 + a01 * a21 + a02 * a22;
        g[5] = a10 * a20 + a11 * a21 + a12 * a22;
        g[6] = WI[(size_t)s * (NION * NPART) + i * NPART + ke];
        g[7] = 0.f;
    }
}

__global__ void __launch_bounds__(256, 4)
ppdet_kernel(const float* __restrict__ EQ, const float* __restrict__ RE,
             const float* __restrict__ WSF, const float* __restrict__ BL,
             float* __restrict__ OUT)
{
    extern __shared__ float ls[];
    const int t  = threadIdx.x;
    const int s  = blockIdx.x >> 9;           // spin
    const int b0 = (blockIdx.x & 511) * NB;   // 4 b's per block

    const int l  = t & 63;                    // lane in wave
    const int w  = t >> 6;                    // wave id: owns b = b0+w
    const int c  = l & 15;                    // MFMA col lane
    const int h4 = l >> 4;                    // MFMA k-group
    const int jr = t & 15;                    // row j (env/det)
    const int ke = t >> 4;                    // k-col (env) / matrix p (det)

    // ---- stage RS (transposed [ib][e][j]) + padded gram; drains under GEMM ----
    #pragma unroll
    for (int it = 0; it < 6; ++it) {
        int idx = it * 256 + t;                  // 0..1535 = ibuf*384 + e*16 + j
        int ibuf = idx / 384, rem = idx % 384;
        int e = rem >> 4, j = rem & 15;
        ls[RS_OFF + idx] = RE[((size_t)(b0 + ibuf) * 32 + s * 16 + j) * 24 + e];
    }
    #pragma unroll
    for (int it = 0; it < 4; ++it) {
        int idx = it * 256 + t;                  // 0..1023
        int kk = idx >> 6, rem = idx & 63;
        ls[GRAM_OFF + kk * 72 + rem] = WSF[WS_GRAM_F + s * 1024 + idx];
    }

    // ---- GEMM via MFMA: straight-line named batches, 2-deep x prefetch ----
    {
        const float* xg  = EQ + ((size_t)((b0 + w) * 32 + s * 16 + c)) * DDIM + h4 * 8;
        const uint4* wb1 = (const uint4*)WSF + (size_t)s * 2048;
        const uint4* wb2 = wb1 + 1024;
        f32x4 accp = {0.f, 0.f, 0.f, 0.f}, accj = {0.f, 0.f, 0.f, 0.f};

        XLD(xa, 0)          // 8 x loads (HBM) in flight
        XLD(xb, 1)          // +8
        WLD(wa, 0)          // 8 W loads (L2)
        COMP(xa, wa)        // kb0
        XLD(xc, 2)
        WLD(wq, 1)
        COMP(xb, wq)        // kb1
        XLD(xd, 3)
        WLD(wr, 2)
        COMP(xc, wr)        // kb2
        WLD(wsx, 3)
        COMP(xd, wsx)       // kb3

        const float blv = BL[s * NPART + c];
        #pragma unroll
        for (int q = 0; q < 4; ++q) {     // C: row = h4*4+q, col = c
            ls[LINP_OFF + (w * 16 + h4 * 4 + q) * 20 + c] = accp[q];
            ls[LINJ_OFF + (w * 16 + h4 * 4 + q) * 20 + c] = accj[q] + blv;
        }
    }
    __syncthreads();   // barrier 1: RS + GRAM + LIN ready

    // ---- env: thread (jr, ke); i-outer so gram regs reused across 4 ib ----
    {
        const float4* gp = (const float4*)(ls + GRAM_OFF + ke * 72);
        float ev[NB] = {0.f, 0.f, 0.f, 0.f};
        #pragma unroll
        for (int i = 0; i < 8; ++i) {
            float4 gA = gp[2 * i];           // G0,G1,G2,G3
            float4 gB = gp[2 * i + 1];       // G4,G5,wir,0
            #pragma unroll
            for (int ib = 0; ib < NB; ++ib) {
                const float* rs = ls + RS_OFF + ib * 384;
                float r0 = rs[(i * 3 + 0) * 16 + jr];
                float r1 = rs[(i * 3 + 1) * 16 + jr];
                float r2 = rs[(i * 3 + 2) * 16 + jr];
                float ss = r0 * r0 * gA.x;
                ss = fmaf(r1 * r1, gA.y, ss);
                ss = fmaf(r2 * r2, gA.z, ss);
                float tcr = r0 * r1 * gA.w;
                tcr = fmaf(r0 * r2, gB.x, tcr);
                tcr = fmaf(r1 * r2, gB.y, tcr);
                ss = fmaf(2.f, tcr, ss);
                ss = fmaxf(ss, 0.f);
                ev[ib] = fmaf(gB.z, __expf(-__builtin_amdgcn_sqrtf(ss)), ev[ib]);
            }
        }
        #pragma unroll
        for (int ib = 0; ib < NB; ++ib)
            ls[ENV_OFF + (ib * 16 + jr) * 20 + ke] = ev[ib];
    }
    __syncthreads();   // barrier 2: ENV ready

    // ---- det: sequential over 4 matrices (low reg pressure), bpermute broadcast ----
    const int lanebase4 = (t & 48) << 2;     // byte addr of in-wave group base
    for (int ib = 0; ib < NB; ++ib) {
        float Mr[16];
        const float* lp = ls + LINP_OFF + (ib * 16 + ke) * 20;   // broadcast reads
        const float* lj = ls + LINJ_OFF + (ib * 16 + jr) * 20;
        const float* ev = ls + ENV_OFF  + (ib * 16 + jr) * 20;
        #pragma unroll
        for (int cq = 0; cq < 4; ++cq) {
            float4 a  = *(const float4*)(lp + cq * 4);
            float4 bb = *(const float4*)(lj + cq * 4);
            float4 e  = *(const float4*)(ev + cq * 4);
            Mr[cq * 4 + 0] = (a.x + bb.x) * e.x;
            Mr[cq * 4 + 1] = (a.y + bb.y) * e.y;
            Mr[cq * 4 + 2] = (a.z + bb.z) * e.z;
            Mr[cq * 4 + 3] = (a.w + bb.w) * e.w;
        }
        float detv = 1.f;
        unsigned sel = 0u;
        int inv = 0;
        bool msel = false;
        #pragma unroll
        for (int cc = 0; cc < 16; ++cc) {
            unsigned key = msel ? 0u
                : ((__float_as_uint(fabsf(Mr[cc])) & 0xFFFFFFF0u) | (unsigned)jr);
            DPPMAXU(key, 0x121); DPPMAXU(key, 0x122); DPPMAXU(key, 0x124); DPPMAXU(key, 0x128);
            const int idx = (int)(key & 15u);
            const bool ispiv = (jr == idx) && !msel;
            const int srcaddr = lanebase4 | (idx << 2);
            float Pr[16];
            #pragma unroll
            for (int k2 = cc; k2 < 16; ++k2)
                Pr[k2] = __int_as_float(__builtin_amdgcn_ds_bpermute(
                             srcaddr, __float_as_int(Mr[k2])));
            const float pv = Pr[cc];
            const float f = (msel || ispiv || pv == 0.f) ? 0.f
                          : Mr[cc] * __builtin_amdgcn_rcpf(pv);
            inv += __popc(sel >> (idx + 1));
            sel |= (1u << idx);
            msel = msel || ispiv;
            detv *= pv;
            #pragma unroll
            for (int k2 = cc + 1; k2 < 16; ++k2)
                Mr[k2] = fmaf(-f, Pr[k2], Mr[k2]);
        }
        if (inv & 1) detv = -detv;
        if (jr == 0) ls[DETS_OFF + ib * 16 + ke] = detv;
    }
    __syncthreads();   // barrier 3: DETS ready

    // ---- epilogue: out = x * det, coalesced float4 ----
    #pragma unroll
    for (int ib = 0; ib < NB; ++ib) {
        const size_t base = ((size_t)((b0 + ib) * 32 + s * 16)) * DDIM;
        #pragma unroll
        for (int i2 = 0; i2 < 8; ++i2) {
            int f4i = i2 * 256 + t;
            float dt = ls[DETS_OFF + ib * 16 + (f4i >> 7)];
            float4 xv = ((const float4*)(EQ + base))[f4i];
            ((float4*)(OUT + base))[f4i] =
                make_float4(xv.x * dt, xv.y * dt, xv.z * dt, xv.w * dt);
        }
    }
}

extern "C" void kernel_launch(void* const* d_in, const int* in_sizes, int n_in,
                              void* d_out, int out_size, void* d_ws, size_t ws_size,
                              hipStream_t stream) {
    const float* EQ = (const float*)d_in[0];
    const float* RE = (const float*)d_in[1];
    const float* WL = (const float*)d_in[2];
    const float* BL = (const float*)d_in[3];
    const float* AE = (const float*)d_in[4];
    const float* WI = (const float*)d_in[5];
    float* OUT = (float*)d_out;
    float* WSF = (float*)d_ws;   // 16384 + 2048 floats = 73728 B
    (void)in_sizes; (void)n_in; (void)out_size; (void)ws_size;

    prep_kernel<<<dim3(17), dim3(256), 0, stream>>>(WL, AE, WI, WSF);
    ppdet_kernel<<<dim3(1024), dim3(256), LDS_BYTES, stream>>>(EQ, RE, WSF, BL, OUT);
}